// Round 5
// baseline (67.635 us; speedup 1.0000x reference)
//
#include <hip/hip_runtime.h>

#define NF   13776
#define NFP  13824            // padded to multiple of 64
#define HALF 6888             // NF/2: wave w owns receivers w and w+HALF
#define KMAX 8
#define EPS  1e-8f
#define CBLK 1722             // HALF/4 waves-per-block -> exactly 2 recv/wave

// ---------------------------------------------------------------------------
// Per-face precompute. Packed layout (ids < 6890 fit in 16 bits):
//   lo4[f] = {lox, loy, loz, asfloat(f0 | f2<<16)}
//   hi4[f] = {hix, hiy, hiz, asfloat(f1)}
//   tri[3f..3f+2] = ax ay az bx | by bz cx cy | cz . . .
// Entries [NF, NFP) are +/-INF sentinels that can never overlap anything.
__global__ __launch_bounds__(256) void prep_kernel(
    const float* __restrict__ verts,   // [NV,3]
    const int*   __restrict__ faces,   // [NF*3]
    float4* __restrict__ tri,          // [NFP*3]
    float4* __restrict__ lo4, float4* __restrict__ hi4)
{
    int f = blockIdx.x * blockDim.x + threadIdx.x;
    if (f >= NFP) return;
    if (f >= NF) {
        lo4[f] = make_float4(INFINITY, INFINITY, INFINITY, __int_as_float(-1));
        hi4[f] = make_float4(-INFINITY, -INFINITY, -INFINITY, __int_as_float(-1));
        return;
    }
    int ia = faces[3 * f + 0], ib = faces[3 * f + 1], ic = faces[3 * f + 2];
    float ax = verts[3 * ia + 0], ay = verts[3 * ia + 1], az = verts[3 * ia + 2];
    float bx = verts[3 * ib + 0], by = verts[3 * ib + 1], bz = verts[3 * ib + 2];
    float cx = verts[3 * ic + 0], cy = verts[3 * ic + 1], cz = verts[3 * ic + 2];
    tri[3 * f + 0] = make_float4(ax, ay, az, bx);
    tri[3 * f + 1] = make_float4(by, bz, cx, cy);
    tri[3 * f + 2] = make_float4(cz, 0.f, 0.f, 0.f);
    lo4[f] = make_float4(fminf(ax, fminf(bx, cx)),
                         fminf(ay, fminf(by, cy)),
                         fminf(az, fminf(bz, cz)),
                         __int_as_float((ia & 0xFFFF) | (ic << 16)));
    hi4[f] = make_float4(fmaxf(ax, fmaxf(bx, cx)),
                         fmaxf(ay, fmaxf(by, cy)),
                         fmaxf(az, fmaxf(bz, cz)),
                         __int_as_float(ib));
}

// ---------------------------------------------------------------------------
// Per-vertex conical penalty term: field of triangle s[9] at point (px,py,pz).
// SIGMA=0.5, POINT2PLANE=False, PENALIZE_OUTSIDE=True.
__device__ __forceinline__ float cone_pen_v(const float* s,
                                            float px, float py, float pz) {
    float e0x = s[3] - s[0], e0y = s[4] - s[1], e0z = s[5] - s[2];
    float e1x = s[6] - s[0], e1y = s[7] - s[1], e1z = s[8] - s[2];
    float nx = e0y * e1z - e0z * e1y;
    float ny = e0z * e1x - e0x * e1z;
    float nz = e0x * e1y - e0y * e1x;
    float inv = 1.0f / (sqrtf(nx * nx + ny * ny + nz * nz) + EPS);
    nx *= inv; ny *= inv; nz *= inv;
    const float third = 1.0f / 3.0f;
    float cx = (s[0] + s[3] + s[6]) * third;
    float cy = (s[1] + s[4] + s[7]) * third;
    float cz = (s[2] + s[5] + s[8]) * third;
    float ux = px - cx, uy = py - cy, uz = pz - cz;
    float h = ux * nx + uy * ny + uz * nz;
    float rx = ux - h * nx, ry = uy - h * ny, rz = uz - h * nz;
    float r = sqrtf(rx * rx + ry * ry + rz * rz);
    float radial = fmaxf(0.0f, 1.0f - 2.0f * r);         // 1 - r/SIGMA
    // relu(-h) + relu(h)*exp(-h/SIGMA) == h<0 ? -h : h*exp(-2h)
    float depth = (h < 0.0f) ? -h : h * expf(-2.0f * h);
    float phi = radial * depth;
    return phi * phi;                                     // POINT2PLANE=False
}

// validity of candidate (jlo,jhi) against receiver (rlo,rhi,fa*)
__device__ __forceinline__ bool valid_pair(
    const float4& rlo, const float4& rhi, int fa0, int fa1, int fa2,
    const float4& jlo, const float4& jhi)
{
    bool ov = (rlo.x <= jhi.x) & (jlo.x <= rhi.x)
            & (rlo.y <= jhi.y) & (jlo.y <= rhi.y)
            & (rlo.z <= jhi.z) & (jlo.z <= rhi.z);
    int w0  = __float_as_int(jlo.w);
    int fb0 = w0 & 0xFFFF;
    int fb2 = ((unsigned)w0) >> 16;
    int fb1 = __float_as_int(jhi.w);
    bool share = (fb0 == fa0) | (fb0 == fa1) | (fb0 == fa2)
               | (fb1 == fa0) | (fb1 == fa1) | (fb1 == fa2)
               | (fb2 == fa0) | (fb2 == fa1) | (fb2 == fa2);
    return ov & !share;
}

// ballot + take first (8-nc) set bits; bit order = ascending j = stable top_k
__device__ __forceinline__ void take_hits(bool valid, int base, int lane,
                                          int& nc, int& hj)
{
    unsigned long long mask = __ballot(valid);
    int cnt  = __popcll(mask);
    int take = min(cnt, KMAX - nc);
    if (lane >= nc && lane < nc + take) {
        int t = lane - nc;
        unsigned long long m = mask;
        for (int q = 0; q < t; ++q) m &= (m - 1);
        hj = base + __builtin_ctzll(m);
    }
    nc += take;
}

// one penalty term: lane's (k,d,v) slot of pair (i, hjk); branch-free loads
__device__ __forceinline__ float pen_term(const float4* __restrict__ tri,
                                          int i, int hjk, int d, int v,
                                          bool live)
{
    int jj = max(hjk, 0);
    int si = d ? jj : i;                                  // field source tri
    int qi = d ? i : jj;                                  // query tri
    float4 s0 = tri[3 * si + 0];
    float4 s1 = tri[3 * si + 1];
    float4 s2 = tri[3 * si + 2];
    float4 q0 = tri[3 * qi + 0];
    float4 q1 = tri[3 * qi + 1];
    float4 q2 = tri[3 * qi + 2];
    float px = (v == 0) ? q0.x : ((v == 1) ? q0.w : q1.z);
    float py = (v == 0) ? q0.y : ((v == 1) ? q1.x : q1.w);
    float pz = (v == 0) ? q0.z : ((v == 1) ? q1.y : q2.x);
    float s[9] = { s0.x, s0.y, s0.z, s0.w, s1.x, s1.y, s1.z, s1.w, s2.x };
    float p = cone_pen_v(s, px, py, pz);
    return live ? p : 0.0f;
}

// ---------------------------------------------------------------------------
// Wave w owns receivers w and w+HALF (exactly 2 each, perfectly balanced).
// Chunk-0 candidate data is loaded ONCE and shared by both receivers.
__global__ __launch_bounds__(256) void coll_kernel(
    const float4* __restrict__ tri,
    const float4* __restrict__ lo4, const float4* __restrict__ hi4,
    float* __restrict__ partial)
{
    const int lane = threadIdx.x & 63;
    const int wid  = threadIdx.x >> 6;
    const int gw   = (blockIdx.x * blockDim.x + threadIdx.x) >> 6;

    const int iA = gw;                                    // < HALF
    const int iB = gw + HALF;

    // receiver data (wave-uniform addresses -> broadcast)
    float4 rloA = lo4[iA], rhiA = hi4[iA];
    float4 rloB = lo4[iB], rhiB = hi4[iB];
    int wA0 = __float_as_int(rloA.w);
    int faA0 = wA0 & 0xFFFF, faA2 = ((unsigned)wA0) >> 16;
    int faA1 = __float_as_int(rhiA.w);
    int wB0 = __float_as_int(rloB.w);
    int faB0 = wB0 & 0xFFFF, faB2 = ((unsigned)wB0) >> 16;
    int faB1 = __float_as_int(rhiB.w);

    int ncA = 0, ncB = 0, hjA = -1, hjB = -1;

    // chunk 0: one candidate load, two validity tests
    {
        float4 jlo = lo4[lane], jhi = hi4[lane];
        bool vA = valid_pair(rloA, rhiA, faA0, faA1, faA2, jlo, jhi);
        bool vB = valid_pair(rloB, rhiB, faB0, faB1, faB2, jlo, jhi);
        take_hits(vA, 0, lane, ncA, hjA);
        take_hits(vB, 0, lane, ncB, hjB);
    }
    // rare continuation chunks
    for (int base = 64; base < NFP && ncA < KMAX; base += 64) {
        float4 jlo = lo4[base + lane], jhi = hi4[base + lane];
        bool vA = valid_pair(rloA, rhiA, faA0, faA1, faA2, jlo, jhi);
        take_hits(vA, base, lane, ncA, hjA);
    }
    for (int base = 64; base < NFP && ncB < KMAX; base += 64) {
        float4 jlo = lo4[base + lane], jhi = hi4[base + lane];
        bool vB = valid_pair(rloB, rhiB, faB0, faB1, faB2, jlo, jhi);
        take_hits(vB, base, lane, ncB, hjB);
    }

    // penalty: lane = k*8 + t; k = pair 0..7, t<6 live: d = t>=3, v = t%3
    int k = lane >> 3;
    int t = lane & 7;
    int d = (t >= 3) ? 1 : 0;
    int v = t - 3 * d;
    int hjkA = __shfl(hjA, k);
    int hjkB = __shfl(hjB, k);
    bool liveT = (t < 6);
    float acc = pen_term(tri, iA, hjkA, d, v, liveT & (k < ncA))
              + pen_term(tri, iB, hjkB, d, v, liveT & (k < ncB));

    // 64-lane butterfly, block reduce, one plain store per block
#pragma unroll
    for (int off = 32; off > 0; off >>= 1) acc += __shfl_xor(acc, off);
    __shared__ float wsum[4];
    if (lane == 0) wsum[wid] = acc;
    __syncthreads();
    if (threadIdx.x == 0)
        partial[blockIdx.x] = wsum[0] + wsum[1] + wsum[2] + wsum[3];
}

// ---------------------------------------------------------------------------
// Sum the CBLK block partials into the scalar output (overwrites poison).
__global__ __launch_bounds__(256) void reduce_kernel(
    const float* __restrict__ partial, float* __restrict__ out)
{
    float a = 0.0f;
    for (int idx = threadIdx.x; idx < CBLK; idx += 256) a += partial[idx];
#pragma unroll
    for (int off = 32; off > 0; off >>= 1) a += __shfl_xor(a, off);
    __shared__ float ws[4];
    int lane = threadIdx.x & 63, wid = threadIdx.x >> 6;
    if (lane == 0) ws[wid] = a;
    __syncthreads();
    if (threadIdx.x == 0) out[0] = ws[0] + ws[1] + ws[2] + ws[3];
}

// ---------------------------------------------------------------------------
extern "C" void kernel_launch(void* const* d_in, const int* in_sizes, int n_in,
                              void* d_out, int out_size, void* d_ws, size_t ws_size,
                              hipStream_t stream) {
    const float* verts = (const float*)d_in[0];   // [1,NV,3] fp32
    const int*   faces = (const int*)d_in[1];     // [NF*3] int32
    float* out = (float*)d_out;                   // scalar fp32

    float4* tri = (float4*)d_ws;                  // NFP*3 float4  (648 KB)
    float4* lo4 = tri + NFP * 3;                  // NFP float4    (216 KB)
    float4* hi4 = lo4 + NFP;                      // NFP float4    (216 KB)
    float*  partial = (float*)(hi4 + NFP);        // CBLK floats   (  7 KB)

    prep_kernel<<<NFP / 256, 256, 0, stream>>>(verts, faces, tri, lo4, hi4);
    coll_kernel<<<CBLK, 256, 0, stream>>>(tri, lo4, hi4, partial);
    reduce_kernel<<<1, 256, 0, stream>>>(partial, out);
}

// Round 6
// 67.287 us; speedup vs baseline: 1.0052x; 1.0052x over previous
//
#include <hip/hip_runtime.h>

#define NF   13776
#define HALF 6888             // NF/2: wave w owns receivers w and w+HALF
#define KMAX 8
#define EPS  1e-8f
#define CBLK 1722             // HALF/4 waves per block -> exactly 2 recv/wave

// ---------------------------------------------------------------------------
// Per-vertex conical penalty term: field of triangle s[9] at point (px,py,pz).
// SIGMA=0.5, POINT2PLANE=False, PENALIZE_OUTSIDE=True.
__device__ __forceinline__ float cone_pen_v(const float* s,
                                            float px, float py, float pz) {
    float e0x = s[3] - s[0], e0y = s[4] - s[1], e0z = s[5] - s[2];
    float e1x = s[6] - s[0], e1y = s[7] - s[1], e1z = s[8] - s[2];
    float nx = e0y * e1z - e0z * e1y;
    float ny = e0z * e1x - e0x * e1z;
    float nz = e0x * e1y - e0y * e1x;
    float inv = 1.0f / (sqrtf(nx * nx + ny * ny + nz * nz) + EPS);
    nx *= inv; ny *= inv; nz *= inv;
    const float third = 1.0f / 3.0f;
    float cx = (s[0] + s[3] + s[6]) * third;
    float cy = (s[1] + s[4] + s[7]) * third;
    float cz = (s[2] + s[5] + s[8]) * third;
    float ux = px - cx, uy = py - cy, uz = pz - cz;
    float h = ux * nx + uy * ny + uz * nz;
    float rx = ux - h * nx, ry = uy - h * ny, rz = uz - h * nz;
    float r = sqrtf(rx * rx + ry * ry + rz * rz);
    float radial = fmaxf(0.0f, 1.0f - 2.0f * r);         // 1 - r/SIGMA
    // relu(-h) + relu(h)*exp(-h/SIGMA) == h<0 ? -h : h*exp(-2h)
    float depth = (h < 0.0f) ? -h : h * expf(-2.0f * h);
    float phi = radial * depth;
    return phi * phi;                                     // POINT2PLANE=False
}

// load face f's vertex ids + 9 coords (constant-indexed array -> registers)
__device__ __forceinline__ void load_tri(const float* __restrict__ verts,
                                         const int* __restrict__ faces,
                                         int f, float c[9],
                                         int& i0, int& i1, int& i2)
{
    i0 = faces[3 * f + 0]; i1 = faces[3 * f + 1]; i2 = faces[3 * f + 2];
    c[0] = verts[3 * i0 + 0]; c[1] = verts[3 * i0 + 1]; c[2] = verts[3 * i0 + 2];
    c[3] = verts[3 * i1 + 0]; c[4] = verts[3 * i1 + 1]; c[5] = verts[3 * i1 + 2];
    c[6] = verts[3 * i2 + 0]; c[7] = verts[3 * i2 + 1]; c[8] = verts[3 * i2 + 2];
}

// ballot + take first (8-nc) set bits; bit order = ascending j = stable top_k
__device__ __forceinline__ void take_hits(bool valid, int base, int lane,
                                          int& nc, int& hj)
{
    unsigned long long mask = __ballot(valid);
    int cnt  = __popcll(mask);
    int take = min(cnt, KMAX - nc);
    if (lane >= nc && lane < nc + take) {
        int t = lane - nc;
        unsigned long long m = mask;
        for (int q = 0; q < t; ++q) m &= (m - 1);
        hj = base + __builtin_ctzll(m);
    }
    nc += take;
}

// one penalty term for pair (receiver ri[9]/its bbox owner i, partner hjk):
// d=0: field of receiver at partner vertex v; d=1: field of partner at
// receiver vertex v. Gathers partner coords directly from verts/faces.
__device__ __forceinline__ float pen_term(const float* __restrict__ verts,
                                          const int* __restrict__ faces,
                                          const float ri[9],
                                          int hjk, int d, int v, bool live)
{
    int jj = max(hjk, 0);
    int b0, b1, b2;
    float jc[9];
    load_tri(verts, faces, jj, jc, b0, b1, b2);
    float s[9];
#pragma unroll
    for (int q = 0; q < 9; ++q) s[q] = d ? jc[q] : ri[q];
    // query point: vertex v of the "other" triangle (ternary avoids dynamic
    // local-array indexing -> no scratch)
    float qx = d ? ((v == 0) ? ri[0] : (v == 1) ? ri[3] : ri[6])
                 : ((v == 0) ? jc[0] : (v == 1) ? jc[3] : jc[6]);
    float qy = d ? ((v == 0) ? ri[1] : (v == 1) ? ri[4] : ri[7])
                 : ((v == 0) ? jc[1] : (v == 1) ? jc[4] : jc[7]);
    float qz = d ? ((v == 0) ? ri[2] : (v == 1) ? ri[5] : ri[8])
                 : ((v == 0) ? jc[2] : (v == 1) ? jc[5] : jc[8]);
    float p = cone_pen_v(s, qx, qy, qz);
    return live ? p : 0.0f;
}

// candidate validity: compute candidate j's bbox + ids on the fly
__device__ __forceinline__ void candidate(const float* __restrict__ verts,
                                          const int* __restrict__ faces, int j,
                                          float lo[3], float hi[3],
                                          int& b0, int& b1, int& b2)
{
    if (j < NF) {
        float c[9];
        load_tri(verts, faces, j, c, b0, b1, b2);
        lo[0] = fminf(c[0], fminf(c[3], c[6]));
        lo[1] = fminf(c[1], fminf(c[4], c[7]));
        lo[2] = fminf(c[2], fminf(c[5], c[8]));
        hi[0] = fmaxf(c[0], fmaxf(c[3], c[6]));
        hi[1] = fmaxf(c[1], fmaxf(c[4], c[7]));
        hi[2] = fmaxf(c[2], fmaxf(c[5], c[8]));
    } else {
        lo[0] = lo[1] = lo[2] = INFINITY;
        hi[0] = hi[1] = hi[2] = -INFINITY;
        b0 = b1 = b2 = -1;
    }
}

__device__ __forceinline__ bool valid_pair(const float rlo[3], const float rhi[3],
                                           int fa0, int fa1, int fa2,
                                           const float lo[3], const float hi[3],
                                           int b0, int b1, int b2)
{
    bool ov = (rlo[0] <= hi[0]) & (lo[0] <= rhi[0])
            & (rlo[1] <= hi[1]) & (lo[1] <= rhi[1])
            & (rlo[2] <= hi[2]) & (lo[2] <= rhi[2]);
    bool share = (b0 == fa0) | (b0 == fa1) | (b0 == fa2)
               | (b1 == fa0) | (b1 == fa1) | (b1 == fa2)
               | (b2 == fa0) | (b2 == fa1) | (b2 == fa2);
    return ov & !share;
}

// ---------------------------------------------------------------------------
// Fully fused: no prep pass, no materialized bboxes/triangles. Wave w owns
// receivers w and w+HALF. 64 lanes test 64 candidates per chunk; ballot bits
// in lane order = ascending j, reproducing stable top_k exactly.
__global__ __launch_bounds__(256) void coll_kernel(
    const float* __restrict__ verts,   // [NV,3]
    const int*   __restrict__ faces,   // [NF*3]
    float* __restrict__ partial)
{
    const int lane = threadIdx.x & 63;
    const int wid  = threadIdx.x >> 6;
    const int gw   = (blockIdx.x * blockDim.x + threadIdx.x) >> 6;

    const int iA = gw;                                    // < HALF
    const int iB = gw + HALF;

    // receiver coords + bboxes (wave-uniform addresses -> broadcast loads);
    // coords stay in registers for the penalty phase.
    float rA[9], rB[9];
    int faA0, faA1, faA2, faB0, faB1, faB2;
    load_tri(verts, faces, iA, rA, faA0, faA1, faA2);
    load_tri(verts, faces, iB, rB, faB0, faB1, faB2);
    float rloA[3] = { fminf(rA[0], fminf(rA[3], rA[6])),
                      fminf(rA[1], fminf(rA[4], rA[7])),
                      fminf(rA[2], fminf(rA[5], rA[8])) };
    float rhiA[3] = { fmaxf(rA[0], fmaxf(rA[3], rA[6])),
                      fmaxf(rA[1], fmaxf(rA[4], rA[7])),
                      fmaxf(rA[2], fmaxf(rA[5], rA[8])) };
    float rloB[3] = { fminf(rB[0], fminf(rB[3], rB[6])),
                      fminf(rB[1], fminf(rB[4], rB[7])),
                      fminf(rB[2], fminf(rB[5], rB[8])) };
    float rhiB[3] = { fmaxf(rB[0], fmaxf(rB[3], rB[6])),
                      fmaxf(rB[1], fmaxf(rB[4], rB[7])),
                      fmaxf(rB[2], fmaxf(rB[5], rB[8])) };

    int ncA = 0, ncB = 0, hjA = -1, hjB = -1;

    // chunk 0: one candidate bbox computation, two validity tests
    {
        float lo[3], hi[3]; int b0, b1, b2;
        candidate(verts, faces, lane, lo, hi, b0, b1, b2);
        bool vA = valid_pair(rloA, rhiA, faA0, faA1, faA2, lo, hi, b0, b1, b2);
        bool vB = valid_pair(rloB, rhiB, faB0, faB1, faB2, lo, hi, b0, b1, b2);
        take_hits(vA, 0, lane, ncA, hjA);
        take_hits(vB, 0, lane, ncB, hjB);
    }
    // rare continuation chunks
    for (int base = 64; base < NF && ncA < KMAX; base += 64) {
        float lo[3], hi[3]; int b0, b1, b2;
        candidate(verts, faces, base + lane, lo, hi, b0, b1, b2);
        bool vA = valid_pair(rloA, rhiA, faA0, faA1, faA2, lo, hi, b0, b1, b2);
        take_hits(vA, base, lane, ncA, hjA);
    }
    for (int base = 64; base < NF && ncB < KMAX; base += 64) {
        float lo[3], hi[3]; int b0, b1, b2;
        candidate(verts, faces, base + lane, lo, hi, b0, b1, b2);
        bool vB = valid_pair(rloB, rhiB, faB0, faB1, faB2, lo, hi, b0, b1, b2);
        take_hits(vB, base, lane, ncB, hjB);
    }

    // penalty: lane = k*8 + t; k = pair 0..7, t<6 live: d = t>=3, v = t%3
    int k = lane >> 3;
    int t = lane & 7;
    int d = (t >= 3) ? 1 : 0;
    int v = t - 3 * d;
    int hjkA = __shfl(hjA, k);
    int hjkB = __shfl(hjB, k);
    bool liveT = (t < 6);
    float acc = pen_term(verts, faces, rA, hjkA, d, v, liveT & (k < ncA))
              + pen_term(verts, faces, rB, hjkB, d, v, liveT & (k < ncB));

    // 64-lane butterfly, block reduce, one plain store per block
#pragma unroll
    for (int off = 32; off > 0; off >>= 1) acc += __shfl_xor(acc, off);
    __shared__ float wsum[4];
    if (lane == 0) wsum[wid] = acc;
    __syncthreads();
    if (threadIdx.x == 0)
        partial[blockIdx.x] = wsum[0] + wsum[1] + wsum[2] + wsum[3];
}

// ---------------------------------------------------------------------------
// Sum the CBLK block partials into the scalar output (overwrites poison).
__global__ __launch_bounds__(256) void reduce_kernel(
    const float* __restrict__ partial, float* __restrict__ out)
{
    float a = 0.0f;
    for (int idx = threadIdx.x; idx < CBLK; idx += 256) a += partial[idx];
#pragma unroll
    for (int off = 32; off > 0; off >>= 1) a += __shfl_xor(a, off);
    __shared__ float ws[4];
    int lane = threadIdx.x & 63, wid = threadIdx.x >> 6;
    if (lane == 0) ws[wid] = a;
    __syncthreads();
    if (threadIdx.x == 0) out[0] = ws[0] + ws[1] + ws[2] + ws[3];
}

// ---------------------------------------------------------------------------
extern "C" void kernel_launch(void* const* d_in, const int* in_sizes, int n_in,
                              void* d_out, int out_size, void* d_ws, size_t ws_size,
                              hipStream_t stream) {
    const float* verts = (const float*)d_in[0];   // [1,NV,3] fp32
    const int*   faces = (const int*)d_in[1];     // [NF*3] int32
    float* out = (float*)d_out;                   // scalar fp32

    float* partial = (float*)d_ws;                // CBLK floats (~7 KB)

    coll_kernel<<<CBLK, 256, 0, stream>>>(verts, faces, partial);
    reduce_kernel<<<1, 256, 0, stream>>>(partial, out);
}